// Round 18
// baseline (339.984 us; speedup 1.0000x reference)
//
#include <hip/hip_runtime.h>

typedef __attribute__((ext_vector_type(8))) short bf16x8;
typedef __attribute__((ext_vector_type(4))) float f32x4;
typedef unsigned short u16;
typedef unsigned int u32;

#define SCALE_ 0.17677669529663687f   // 32^-0.5
#define MFMA(a,b,c) __builtin_amdgcn_mfma_f32_16x16x32_bf16(a,b,c,0,0,0)

__device__ __forceinline__ u16 f2bf(float f){
    u32 u = __float_as_uint(f);
    u = (u + 0x7FFFu + ((u >> 16) & 1u)) >> 16;
    return (u16)u;
}
__device__ __forceinline__ float bf2f(u32 h){ return __uint_as_float(h << 16); }
__device__ __forceinline__ u32 pk2(float a, float b){ return (u32)f2bf(a) | ((u32)f2bf(b) << 16); }

// Build an 8-element (K-octet) MFMA fragment from packed C-tiles via shuffles.
__device__ __forceinline__ bf16x8 frag8(uint2 p0, uint2 p1, int kg, int l15){
    const int s0 = ((kg & 1) << 5) + l15;
    const int s1 = s0 + 16;
    u32 a0 = (u32)__shfl((int)p0.x, s0, 64);
    u32 a1 = (u32)__shfl((int)p0.y, s0, 64);
    u32 a2 = (u32)__shfl((int)p0.x, s1, 64);
    u32 a3 = (u32)__shfl((int)p0.y, s1, 64);
    u32 b0 = (u32)__shfl((int)p1.x, s0, 64);
    u32 b1 = (u32)__shfl((int)p1.y, s0, 64);
    u32 b2 = (u32)__shfl((int)p1.x, s1, 64);
    u32 b3 = (u32)__shfl((int)p1.y, s1, 64);
    const bool hi = (kg >= 2);
    union { u32 u[4]; bf16x8 v; } r;
    r.u[0] = hi ? b0 : a0; r.u[1] = hi ? b1 : a1;
    r.u[2] = hi ? b2 : a2; r.u[3] = hi ? b3 : a3;
    return r.v;
}

// ws layout (u16 units):
//   [0,      196608)  W rows (Wq 0-255, Wk 256-511, Wv 512-767) row-major
//   [196608, 262144)  Wproj rows
//   [262144, 263424)  rpe_pk: (j*8 + h)*32 + hd
//   [263424, 263680)  w1_pk:  h*32 + hd              (fallback path)
//   [263680, 267776)  w1full: 16x256, row h: w1[h] in cols [h*32,h*32+32), else 0
//   [267776, 333312)  WvT packed per head (fallback path)
//   [333312, +3840*8*2624)  pages: per (n,t,h): q_pk 800 | ke_pk 800 | v_pk 1024
//   bias_ws (f32): 3840*256 at u16 index 80942592
#define PG_OFF_ 333312
#define NPAGES_ ((size_t)3840*8*2624)     // 80,609,280 u16
#define BIAS_U16_ (PG_OFF_ + NPAGES_)     // 80,942,592

__global__ void prep_kernel(const float* __restrict__ Wkv, const float* __restrict__ Wq,
                            const float* __restrict__ Wproj, const float* __restrict__ rpe,
                            const float* __restrict__ w1, u16* __restrict__ wpk)
{
    int i = blockIdx.x * 256 + threadIdx.x;
    if (i < 65536)        wpk[i] = f2bf(Wq[i]);
    else if (i < 196608)  wpk[i] = f2bf(Wkv[i - 65536]);
    else if (i < 262144)  wpk[i] = f2bf(Wproj[i - 196608]);
    else if (i < 263424){
        int j = i - 262144;
        int jj = j >> 8, h = (j >> 5) & 7, hd = j & 31;
        wpk[i] = f2bf(rpe[jj*256 + h*32 + hd]);
    }
    else if (i < 263680)  wpk[i] = f2bf(w1[i - 263424]);
    else if (i < 267776){
        int j = i - 263680;
        int r = j >> 8, c = j & 255;
        float v = (r < 8 && (c >> 5) == r) ? w1[r*32 + (c & 31)] : 0.f;
        wpk[i] = f2bf(v);
    }
    else if (i < 333312){
        int j = i - 267776;
        int h = j >> 13;
        int r = j & 8191;
        int coct = r >> 8, hd = (r >> 3) & 31, clo = r & 7;
        wpk[i] = f2bf(Wkv[(size_t)(256 + h*32 + hd) * 256 + coct*8 + clo]);
    }
}

// ============ kernel 1: QKV GEMM, one (n,t) per block =======================
// 256-thread / 4-wave blocks, col-tile 25 (= one t). Stage X AND E once,
// loop ALL 768 W-rows in 6 passes of 128 (4 waves x 32); k-passes fold E
// from its own buffer; wave 0 runs the w1-bias mini-GEMM. LDS 25.9KB.
// NO launch-bounds waves hint: R15's (256,6) squeezed VGPR to 40 -> spilled
// (WRITE 437MB); unhinted 256-thread blocks schedule freely (R14: 84% occ)
// and natural VGPR ~50-64 fits 4-6 blocks/CU.
__launch_bounds__(256)
__global__ void qkv_gemm(const float* __restrict__ x, const float* __restrict__ e,
                         const u16* __restrict__ wpk, u16* __restrict__ pages,
                         float* __restrict__ bias_ws)
{
    __shared__ __align__(16) u16 xs[6464];   // X: [coct 32][col 25][8] + pad
    __shared__ __align__(16) u16 es[6464];   // E: same layout + pad

    const int tid = threadIdx.x;             // 256
    const int w = tid >> 6, lane = tid & 63;
    const int l15 = lane & 15, kg = lane >> 4;
    const int wg = ((int)blockIdx.x & 7) * 480 + ((int)blockIdx.x >> 3);  // XCD swizzle
    const int n = wg / 120, t = wg % 120;
    const f32x4 zf = {0.f, 0.f, 0.f, 0.f};

    // ---- stage X and E (transpose-gather, conflict-free b128 writes) ----
    const float* xb = x + (size_t)n*768000 + t*25;
    const float* eb = e + (size_t)n*768000 + t*25;
    for (int i = tid; i < 1600; i += 256){
        int j = i < 800 ? i : i - 800;
        int col = j % 25, coct = j / 25;
        const float* src = (i < 800 ? xb : eb) + (size_t)(coct*8)*3000 + col;
        u32 p[4];
        #pragma unroll
        for (int r2 = 0; r2 < 4; ++r2)
            p[r2] = pk2(src[(2*r2)*3000], src[(2*r2+1)*3000]);
        u16* dst = (i < 800 ? xs : es);
        *(uint4*)&dst[(coct*25 + col)*8] = *(const uint4*)p;
    }
    __syncthreads();

    u16* pgbase = pages + (size_t)wg * 8 * 2624;

    // ---- 6 passes x 128 rows: q (p0,1), k+Efold (p2,3), v (p4,5) ----
    for (int p = 0; p < 6; ++p){
        const int sec = p >> 1;
        const int rb  = (p & 1) * 128 + w * 32;          // within-sec row base
        f32x4 acc[2][2];
        #pragma unroll
        for (int m = 0; m < 2; ++m){ acc[m][0] = zf; acc[m][1] = zf; }

        const u16* wrow = wpk + (size_t)(sec*256 + rb + l15) * 256;
        #pragma unroll
        for (int ks = 0; ks < 8; ++ks){
            bf16x8 a0 = *(const bf16x8*)(wrow + ks*32 + kg*8);
            bf16x8 a1 = *(const bf16x8*)(wrow + 4096 + ks*32 + kg*8);
            #pragma unroll
            for (int f = 0; f < 2; ++f){
                bf16x8 b = *(const bf16x8*)&xs[((ks*4+kg)*25 + f*16 + l15)*8];
                acc[0][f] = MFMA(a0, b, acc[0][f]);
                acc[1][f] = MFMA(a1, b, acc[1][f]);
            }
        }

        if (sec == 1){   // fold E (its own buffer -- no restage)
            #pragma unroll
            for (int m = 0; m < 2; ++m){
                int c0 = rb + m*16 + kg*4;
                #pragma unroll
                for (int f = 0; f < 2; ++f){
                    uint2 ev = *(const uint2*)&es[((c0>>3)*25 + f*16 + l15)*8 + (c0&7)];
                    acc[m][f][0] += bf2f(ev.x & 0xFFFFu);
                    acc[m][f][1] += bf2f(ev.x >> 16);
                    acc[m][f][2] += bf2f(ev.y & 0xFFFFu);
                    acc[m][f][3] += bf2f(ev.y >> 16);
                }
            }
        }

        // write packed page section
        const int secoff = (sec == 0) ? 0 : (sec == 1 ? 800 : 1600);
        const int h = rb >> 5;                            // head = row/32
        u16* pg = pgbase + h*2624 + secoff;
        #pragma unroll
        for (int m = 0; m < 2; ++m){
            int hd0 = m*16 + kg*4;
            #pragma unroll
            for (int f = 0; f < 2; ++f){
                int a = f*16 + l15;
                if (a < 25){
                    if (sec < 2){
                        uint2 val; val.x = pk2(acc[m][f][0], acc[m][f][1]);
                        val.y = pk2(acc[m][f][2], acc[m][f][3]);
                        *(uint2*)&pg[((hd0>>3)*25 + a)*8 + (hd0&7)] = val;
                    } else {
                        #pragma unroll
                        for (int r2 = 0; r2 < 4; ++r2)
                            pg[((a>>3)*32 + hd0 + r2)*8 + (a&7)] = f2bf(acc[m][f][r2]);
                    }
                }
            }
        }
    }

    // ---- bias = w1full @ E (wave 0) ----
    if (w == 0){
        f32x4 bacc[2];
        bacc[0] = zf; bacc[1] = zf;
        const u16* w1f = wpk + 263680 + l15*256;
        #pragma unroll
        for (int ks = 0; ks < 8; ++ks){
            bf16x8 a = *(const bf16x8*)(w1f + ks*32 + kg*8);
            #pragma unroll
            for (int f = 0; f < 2; ++f){
                bf16x8 b = *(const bf16x8*)&es[((ks*4+kg)*25 + f*16 + l15)*8];
                bacc[f] = MFMA(a, b, bacc[f]);
            }
        }
        if (kg < 2){
            #pragma unroll
            for (int f = 0; f < 2; ++f){
                int a = f*16 + l15;
                if (a < 25){
                    #pragma unroll
                    for (int r2 = 0; r2 < 4; ++r2)
                        bias_ws[(size_t)wg*256 + (kg*4+r2)*32 + a] = bacc[f][r2];
                }
            }
        }
    }
}

// ============ kernel 2: attention + proj, reading packed pages ==============
// Per (n,t): 8 waves = 8 heads. q/ke/v fragments = single b128 global loads.
__launch_bounds__(512)
__global__ void attn_proj(const float* __restrict__ outer, const float* __restrict__ alpha,
                          const float* __restrict__ bproj, const u16* __restrict__ wpk,
                          const u16* __restrict__ pages, const float* __restrict__ bias_ws,
                          float* __restrict__ out)
{
    __shared__ __align__(16) u16 opk[6656 + 64];

    const int tid = threadIdx.x;
    const int w = tid >> 6, lane = tid & 63;
    const int l15 = lane & 15, kg = lane >> 4;
    const int wg = ((int)blockIdx.x & 7) * 480 + ((int)blockIdx.x >> 3);
    const int n = wg / 120, t = wg % 120;
    const float alpha0 = alpha[0];
    const f32x4 zf = {0.f, 0.f, 0.f, 0.f};
    const int h = w;
    const u16* pg = pages + ((size_t)wg*8 + h)*2624;

    bf16x8 fq0  = *(const bf16x8*)&pg[(kg*25 + l15)*8];
    bf16x8 fq1  = *(const bf16x8*)&pg[(kg*25 + 16 + l15)*8];
    bf16x8 fke0 = *(const bf16x8*)&pg[800 + (kg*25 + l15)*8];
    bf16x8 fke1;
    if (l15 < 9)       fke1 = *(const bf16x8*)&pg[800 + (kg*25 + 16 + l15)*8];
    else if (l15 <= 13) fke1 = *(const bf16x8*)(wpk + 262144 + ((l15-9)*8 + h)*32 + kg*8);
    else { union { u32 u[4]; bf16x8 v; } z; z.u[0]=z.u[1]=z.u[2]=z.u[3]=0; fke1 = z.v; }

    f32x4 sc[2][2];
    sc[0][0] = MFMA(fke0, fq0, zf);
    sc[0][1] = MFMA(fke0, fq1, zf);
    sc[1][0] = MFMA(fke1, fq0, zf);
    sc[1][1] = MFMA(fke1, fq1, zf);

    float bias01[2];
    bias01[0] = bias_ws[(size_t)wg*256 + h*32 + l15];
    bias01[1] = bias_ws[(size_t)wg*256 + h*32 + 16 + l15];

    uint2 P_G[2][2];
    #pragma unroll
    for (int nt = 0; nt < 2; ++nt){
        const int a = nt*16 + l15;
        f32x4 s0 = sc[0][nt], s1 = sc[1][nt];
        float rr0 = __shfl(s1[1], 32 + l15, 64);
        float rr1 = __shfl(s1[2], 32 + l15, 64);
        float rr2 = __shfl(s1[3], 32 + l15, 64);
        float rr3 = __shfl(s1[0], 48 + l15, 64);
        float rr4 = __shfl(s1[1], 48 + l15, 64);
        float tv[8];
        #pragma unroll
        for (int mt = 0; mt < 2; ++mt)
            #pragma unroll
            for (int r = 0; r < 4; ++r){
                int b = mt*16 + kg*4 + r;
                float sval = mt ? s1[r] : s0[r];
                float bb = __shfl(bias01[mt], (lane & 48) + (b & 15), 64);
                int d = a - b; d = d < 0 ? -d : d; if (d > 4) d = 4;
                float rj = d==0?rr0 : d==1?rr1 : d==2?rr2 : d==3?rr3 : rr4;
                float tt = (sval + rj + bb) * SCALE_;
                tv[mt*4+r] = (b < 25) ? tt : -1e30f;
            }
        float m = tv[0];
        #pragma unroll
        for (int i = 1; i < 8; ++i) m = fmaxf(m, tv[i]);
        m = fmaxf(m, __shfl_xor(m, 16, 64));
        m = fmaxf(m, __shfl_xor(m, 32, 64));
        float ex[8], sm = 0.f;
        #pragma unroll
        for (int i = 0; i < 8; ++i){ ex[i] = __expf(tv[i] - m); sm += ex[i]; }
        sm += __shfl_xor(sm, 16, 64);
        sm += __shfl_xor(sm, 32, 64);
        const float inv = alpha0 / sm;
        float g[8];
        #pragma unroll
        for (int mt = 0; mt < 2; ++mt)
            #pragma unroll
            for (int r = 0; r < 4; ++r){
                int b = mt*16 + kg*4 + r;
                float ov = (a < 25 && b < 25) ? outer[((size_t)h*25 + a)*25 + b] : 0.f;
                g[mt*4+r] = (b < 25) ? ex[mt*4+r]*inv + ov : 0.f;
            }
        uint2 pg0; pg0.x = pk2(g[0], g[1]); pg0.y = pk2(g[2], g[3]);
        uint2 pg1; pg1.x = pk2(g[4], g[5]); pg1.y = pk2(g[6], g[7]);
        P_G[nt][0] = pg0; P_G[nt][1] = pg1;
    }

    {
        bf16x8 fv0 = *(const bf16x8*)&pg[1600 + (kg*32 + l15)*8];
        bf16x8 fv1 = *(const bf16x8*)&pg[1600 + (kg*32 + 16 + l15)*8];
        bf16x8 fg0 = frag8(P_G[0][0], P_G[0][1], kg, l15);
        bf16x8 fg1 = frag8(P_G[1][0], P_G[1][1], kg, l15);
        f32x4 o[2][2];
        o[0][0] = MFMA(fv0, fg0, zf); o[0][1] = MFMA(fv0, fg1, zf);
        o[1][0] = MFMA(fv1, fg0, zf); o[1][1] = MFMA(fv1, fg1, zf);
        #pragma unroll
        for (int mt = 0; mt < 2; ++mt)
            #pragma unroll
            for (int nt = 0; nt < 2; ++nt){
                int a = nt*16 + l15;
                if (a < 25){
                    int coct = h*4 + mt*2 + (kg>>1);
                    u32* dst = (u32*)&opk[(coct*26 + a)*8 + (kg&1)*4];
                    dst[0] = pk2(o[mt][nt][0], o[mt][nt][1]);
                    dst[1] = pk2(o[mt][nt][2], o[mt][nt][3]);
                }
            }
    }
    __syncthreads();

    {
        f32x4 pc[2][2];
        #pragma unroll
        for (int i = 0; i < 2; ++i){ pc[i][0] = zf; pc[i][1] = zf; }
        #pragma unroll
        for (int ks = 0; ks < 8; ++ks){
            bf16x8 pb0 = *(const bf16x8*)&opk[((ks*4+kg)*26 + l15)*8];
            bf16x8 pb1 = *(const bf16x8*)&opk[((ks*4+kg)*26 + 16 + l15)*8];
            #pragma unroll
            for (int i = 0; i < 2; ++i){
                bf16x8 aw = *(const bf16x8*)(wpk + 196608 +
                                (size_t)(w*32 + i*16 + l15)*256 + ks*32 + kg*8);
                pc[i][0] = MFMA(aw, pb0, pc[i][0]);
                pc[i][1] = MFMA(aw, pb1, pc[i][1]);
            }
        }
        #pragma unroll
        for (int i = 0; i < 2; ++i){
            const int d = w*32 + i*16 + kg*4;
            float b0 = bproj[d], b1 = bproj[d+1], b2 = bproj[d+2], b3 = bproj[d+3];
            #pragma unroll
            for (int nt = 0; nt < 2; ++nt){
                int v = nt*16 + l15;
                if (v < 25){
                    float* op = out + (size_t)n*768000 + (size_t)d*3000 + t*25 + v;
                    op[0]    = pc[i][nt][0] + b0;
                    op[3000] = pc[i][nt][1] + b1;
                    op[6000] = pc[i][nt][2] + b2;
                    op[9000] = pc[i][nt][3] + b3;
                }
            }
        }
    }
}

// ============== FALLBACK: fused kernel (R7, 303us) ==========================
__launch_bounds__(512, 4)
__global__ void mhsa_main(const float* __restrict__ x, const float* __restrict__ e,
                          const float* __restrict__ outer, const float* __restrict__ alpha,
                          const float* __restrict__ bproj, const u16* __restrict__ wpk,
                          float* __restrict__ out)
{
    __shared__ __align__(16) u16 smem[6656*3 + 64];
    u16* xs  = smem;
    u16* es  = smem + 6656;
    u16* opk = smem + 13312;

    const int tid = threadIdx.x;
    const int w = tid >> 6, lane = tid & 63;
    const int l15 = lane & 15, kg = lane >> 4;
    const int wg = (blockIdx.x & 7) * 480 + (blockIdx.x >> 3);
    const int n = wg / 120, t = wg % 120;
    const float alpha0 = alpha[0];
    const f32x4 zf = {0.f, 0.f, 0.f, 0.f};

    const float* xb = x + (size_t)n*768000 + t*25;
    const float* eb = e + (size_t)n*768000 + t*25;
    for (int i = tid; i < 6400; i += 512){
        int c = i / 25, v = i - c*25;
        int a16 = ((c>>3)*26 + v)*8 + (c&7);
        xs[a16] = f2bf(xb[c*3000 + v]);
        es[a16] = f2bf(eb[c*3000 + v]);
    }
    __syncthreads();

    {
        const int h = w;
        f32x4 cq[2][2], ck[2][2];
        #pragma unroll
        for (int i = 0; i < 2; ++i)
            #pragma unroll
            for (int j = 0; j < 2; ++j){ cq[i][j] = zf; ck[i][j] = zf; }
        {
            const u16* wq0 = wpk + (size_t)(h*32 + l15)*256;
            const u16* wk0 = wpk + 65536 + (size_t)(h*32 + l15)*256;
            #pragma unroll
            for (int ks = 0; ks < 8; ++ks){
                bf16x8 b0 = *(const bf16x8*)&xs[((ks*4+kg)*26 + l15)*8];
                bf16x8 b1 = *(const bf16x8*)&xs[((ks*4+kg)*26 + 16 + l15)*8];
                bf16x8 aq0 = *(const bf16x8*)(wq0 + ks*32 + kg*8);
                bf16x8 aq1 = *(const bf16x8*)(wq0 + 4096 + ks*32 + kg*8);
                bf16x8 ak0 = *(const bf16x8*)(wk0 + ks*32 + kg*8);
                bf16x8 ak1 = *(const bf16x8*)(wk0 + 4096 + ks*32 + kg*8);
                cq[0][0]=MFMA(aq0,b0,cq[0][0]); cq[0][1]=MFMA(aq0,b1,cq[0][1]);
                cq[1][0]=MFMA(aq1,b0,cq[1][0]); cq[1][1]=MFMA(aq1,b1,cq[1][1]);
                ck[0][0]=MFMA(ak0,b0,ck[0][0]); ck[0][1]=MFMA(ak0,b1,ck[0][1]);
                ck[1][0]=MFMA(ak1,b0,ck[1][0]); ck[1][1]=MFMA(ak1,b1,ck[1][1]);
            }
        }
        uint2 P_q[2][2], P_k[2][2];
        #pragma unroll
        for (int mt = 0; mt < 2; ++mt)
            #pragma unroll
            for (int nt = 0; nt < 2; ++nt){
                int coct = h*4 + mt*2 + (kg>>1);
                uint2 ev = *(const uint2*)&es[(coct*26 + nt*16 + l15)*8 + (kg&1)*4];
                ck[mt][nt][0] += bf2f(ev.x & 0xFFFFu);
                ck[mt][nt][1] += bf2f(ev.x >> 16);
                ck[mt][nt][2] += bf2f(ev.y & 0xFFFFu);
                ck[mt][nt][3] += bf2f(ev.y >> 16);
                uint2 pq; pq.x = pk2(cq[mt][nt][0], cq[mt][nt][1]);
                pq.y = pk2(cq[mt][nt][2], cq[mt][nt][3]);
                P_q[nt][mt] = pq;
                uint2 pk; pk.x = pk2(ck[mt][nt][0], ck[mt][nt][1]);
                pk.y = pk2(ck[mt][nt][2], ck[mt][nt][3]);
                P_k[nt][mt] = pk;
            }
        float bias01[2];
        {
            bf16x8 aw1 = *(const bf16x8*)(wpk + 263424 + h*32 + kg*8);
            bf16x8 be0 = *(const bf16x8*)&es[((h*4+kg)*26 + l15)*8];
            bf16x8 be1 = *(const bf16x8*)&es[((h*4+kg)*26 + 16 + l15)*8];
            f32x4 cb0 = MFMA(aw1, be0, zf);
            f32x4 cb1 = MFMA(aw1, be1, zf);
            bias01[0] = cb0[0]; bias01[1] = cb1[0];
        }
        f32x4 cv[2][2];
        #pragma unroll
        for (int i = 0; i < 2; ++i)
            #pragma unroll
            for (int j = 0; j < 2; ++j) cv[i][j] = zf;
        {
            const u16* wvt = wpk + 267776 + h*8192;
            #pragma unroll
            for (int ks = 0; ks < 8; ++ks){
                bf16x8 a0 = *(const bf16x8*)&xs[((ks*4+kg)*26 + l15)*8];
                bf16x8 a1 = *(const bf16x8*)&xs[((ks*4+kg)*26 + 16 + l15)*8];
                bf16x8 bv0 = *(const bf16x8*)&wvt[((ks*4+kg)*32 + l15)*8];
                bf16x8 bv1 = *(const bf16x8*)&wvt[((ks*4+kg)*32 + 16 + l15)*8];
                cv[0][0]=MFMA(a0,bv0,cv[0][0]); cv[0][1]=MFMA(a0,bv1,cv[0][1]);
                cv[1][0]=MFMA(a1,bv0,cv[1][0]); cv[1][1]=MFMA(a1,bv1,cv[1][1]);
            }
        }
        #pragma unroll
        for (int nt = 0; nt < 2; ++nt)
            #pragma unroll
            for (int r = 0; r < 4; ++r)
                cv[1][nt][r] = (kg*4 + r < 9) ? cv[1][nt][r] : 0.f;
        uint2 P_v[2][2];
        #pragma unroll
        for (int mt = 0; mt < 2; ++mt)
            #pragma unroll
            for (int nt = 0; nt < 2; ++nt){
                uint2 pv; pv.x = pk2(cv[mt][nt][0], cv[mt][nt][1]);
                pv.y = pk2(cv[mt][nt][2], cv[mt][nt][3]);
                P_v[nt][mt] = pv;
            }
        bf16x8 fq0  = frag8(P_q[0][0], P_q[0][1], kg, l15);
        bf16x8 fq1  = frag8(P_q[1][0], P_q[1][1], kg, l15);
        bf16x8 fke0 = frag8(P_k[0][0], P_k[0][1], kg, l15);
        bf16x8 fke1 = frag8(P_k[1][0], P_k[1][1], kg, l15);
        if (l15 >= 9){
            if (l15 <= 13)
                fke1 = *(const bf16x8*)(wpk + 262144 + ((l15-9)*8 + h)*32 + kg*8);
            else {
                union { u32 u[4]; bf16x8 v; } z; z.u[0]=z.u[1]=z.u[2]=z.u[3]=0;
                fke1 = z.v;
            }
        }
        f32x4 sc[2][2];
        sc[0][0] = MFMA(fke0, fq0, zf);
        sc[0][1] = MFMA(fke0, fq1, zf);
        sc[1][0] = MFMA(fke1, fq0, zf);
        sc[1][1] = MFMA(fke1, fq1, zf);
        uint2 P_G[2][2];
        #pragma unroll
        for (int nt = 0; nt < 2; ++nt){
            const int a = nt*16 + l15;
            f32x4 s0 = sc[0][nt], s1 = sc[1][nt];
            float rr0 = __shfl(s1[1], 32 + l15, 64);
            float rr1 = __shfl(s1[2], 32 + l15, 64);
            float rr2 = __shfl(s1[3], 32 + l15, 64);
            float rr3 = __shfl(s1[0], 48 + l15, 64);
            float rr4 = __shfl(s1[1], 48 + l15, 64);
            float tv[8];
            #pragma unroll
            for (int mt = 0; mt < 2; ++mt)
                #pragma unroll
                for (int r = 0; r < 4; ++r){
                    int b = mt*16 + kg*4 + r;
                    float sval = mt ? s1[r] : s0[r];
                    float bb = __shfl(bias01[mt], (lane & 48) + (b & 15), 64);
                    int d = a - b; d = d < 0 ? -d : d; if (d > 4) d = 4;
                    float rj = d==0?rr0 : d==1?rr1 : d==2?rr2 : d==3?rr3 : rr4;
                    float tt = (sval + rj + bb) * SCALE_;
                    tv[mt*4+r] = (b < 25) ? tt : -1e30f;
                }
            float m = tv[0];
            #pragma unroll
            for (int i = 1; i < 8; ++i) m = fmaxf(m, tv[i]);
            m = fmaxf(m, __shfl_xor(m, 16, 64));
            m = fmaxf(m, __shfl_xor(m, 32, 64));
            float ex[8], sm = 0.f;
            #pragma unroll
            for (int i = 0; i < 8; ++i){ ex[i] = __expf(tv[i] - m); sm += ex[i]; }
            sm += __shfl_xor(sm, 16, 64);
            sm += __shfl_xor(sm, 32, 64);
            const float inv = alpha0 / sm;
            float g[8];
            #pragma unroll
            for (int mt = 0; mt < 2; ++mt)
                #pragma unroll
                for (int r = 0; r < 4; ++r){
                    int b = mt*16 + kg*4 + r;
                    float ov = (a < 25 && b < 25) ? outer[((size_t)h*25 + a)*25 + b] : 0.f;
                    g[mt*4+r] = (b < 25) ? ex[mt*4+r]*inv + ov : 0.f;
                }
            uint2 pg0; pg0.x = pk2(g[0], g[1]); pg0.y = pk2(g[2], g[3]);
            uint2 pg1; pg1.x = pk2(g[4], g[5]); pg1.y = pk2(g[6], g[7]);
            P_G[nt][0] = pg0; P_G[nt][1] = pg1;
        }
        {
            bf16x8 fv0 = frag8(P_v[0][0], P_v[0][1], kg, l15);
            bf16x8 fv1 = frag8(P_v[1][0], P_v[1][1], kg, l15);
            bf16x8 fg0 = frag8(P_G[0][0], P_G[0][1], kg, l15);
            bf16x8 fg1 = frag8(P_G[1][0], P_G[1][1], kg, l15);
            f32x4 o[2][2];
            o[0][0] = MFMA(fv0, fg0, zf); o[0][1] = MFMA(fv0, fg1, zf);
            o[1][0] = MFMA(fv1, fg0, zf); o[1][1] = MFMA(fv1, fg1, zf);
            #pragma unroll
            for (int mt = 0; mt < 2; ++mt)
                #pragma unroll
                for (int nt = 0; nt < 2; ++nt){
                    int a = nt*16 + l15;
                    if (a < 25){
                        int coct = h*4 + mt*2 + (kg>>1);
                        u32* dst = (u32*)&opk[(coct*26 + a)*8 + (kg&1)*4];
                        dst[0] = pk2(o[mt][nt][0], o[mt][nt][1]);
                        dst[1] = pk2(o[mt][nt][2], o[mt][nt][3]);
                    }
                }
        }
    }
    __syncthreads();

    {
        f32x4 pc[2][2];
        #pragma unroll
        for (int i = 0; i < 2; ++i){ pc[i][0] = zf; pc[i][1] = zf; }
        #pragma unroll
        for (int ks = 0; ks < 8; ++ks){
            bf16x8 pb0 = *(const bf16x8*)&opk[((ks*4+kg)*26 + l15)*8];
            bf16x8 pb1 = *(const bf16x8*)&opk[((ks*4+kg)*26 + 16 + l15)*8];
            #pragma unroll
            for (int i = 0; i < 2; ++i){
                bf16x8 aw = *(const bf16x8*)(wpk + 196608 +
                                (size_t)(w*32 + i*16 + l15)*256 + ks*32 + kg*8);
                pc[i][0] = MFMA(aw, pb0, pc[i][0]);
                pc[i][1] = MFMA(aw, pb1, pc[i][1]);
            }
        }
        #pragma unroll
        for (int i = 0; i < 2; ++i){
            const int d = w*32 + i*16 + kg*4;
            float b0 = bproj[d], b1 = bproj[d+1], b2 = bproj[d+2], b3 = bproj[d+3];
            #pragma unroll
            for (int nt = 0; nt < 2; ++nt){
                int v = nt*16 + l15;
                if (v < 25){
                    float* op = out + (size_t)n*768000 + (size_t)d*3000 + t*25 + v;
                    op[0]    = pc[i][nt][0] + b0;
                    op[3000] = pc[i][nt][1] + b1;
                    op[6000] = pc[i][nt][2] + b2;
                    op[9000] = pc[i][nt][3] + b3;
                }
            }
        }
    }
}

extern "C" void kernel_launch(void* const* d_in, const int* in_sizes, int n_in,
                              void* d_out, int out_size, void* d_ws, size_t ws_size,
                              hipStream_t stream) {
    (void)in_sizes; (void)n_in; (void)out_size;
    const float* x     = (const float*)d_in[0];
    const float* e     = (const float*)d_in[1];
    const float* Wkv   = (const float*)d_in[2];
    const float* Wq    = (const float*)d_in[3];
    const float* Wproj = (const float*)d_in[4];
    const float* bproj = (const float*)d_in[5];
    const float* rpe   = (const float*)d_in[6];
    const float* w1    = (const float*)d_in[7];
    const float* outer = (const float*)d_in[8];
    const float* alpha = (const float*)d_in[9];
    float* out = (float*)d_out;
    u16* wpk = (u16*)d_ws;

    prep_kernel<<<1302, 256, 0, stream>>>(Wkv, Wq, Wproj, rpe, w1, wpk);

    const size_t need = (size_t)BIAS_U16_ * 2 + (size_t)3840*256*4 + 4096;  // ~165.8 MB
    if (ws_size >= need){
        u16* pages = wpk + PG_OFF_;
        float* bias_ws = (float*)(wpk + BIAS_U16_);
        qkv_gemm<<<3840, 256, 0, stream>>>(x, e, wpk, pages, bias_ws);
        attn_proj<<<3840, 512, 0, stream>>>(outer, alpha, bproj, wpk, pages, bias_ws, out);
    } else {
        mhsa_main<<<3840, 512, 0, stream>>>(x, e, outer, alpha, bproj, wpk, out);
    }
}

// Round 19
// 278.459 us; speedup vs baseline: 1.2209x; 1.2209x over previous
//
#include <hip/hip_runtime.h>

typedef __attribute__((ext_vector_type(8))) short bf16x8;
typedef __attribute__((ext_vector_type(4))) float f32x4;
typedef unsigned short u16;
typedef unsigned int u32;

#define SCALE_ 0.17677669529663687f   // 32^-0.5
#define MFMA(a,b,c) __builtin_amdgcn_mfma_f32_16x16x32_bf16(a,b,c,0,0,0)

__device__ __forceinline__ u16 f2bf(float f){
    u32 u = __float_as_uint(f);
    u = (u + 0x7FFFu + ((u >> 16) & 1u)) >> 16;
    return (u16)u;
}
__device__ __forceinline__ float bf2f(u32 h){ return __uint_as_float(h << 16); }
__device__ __forceinline__ u32 pk2(float a, float b){ return (u32)f2bf(a) | ((u32)f2bf(b) << 16); }

// Build an 8-element (K-octet) MFMA fragment from packed C-tiles via shuffles.
__device__ __forceinline__ bf16x8 frag8(uint2 p0, uint2 p1, int kg, int l15){
    const int s0 = ((kg & 1) << 5) + l15;
    const int s1 = s0 + 16;
    u32 a0 = (u32)__shfl((int)p0.x, s0, 64);
    u32 a1 = (u32)__shfl((int)p0.y, s0, 64);
    u32 a2 = (u32)__shfl((int)p0.x, s1, 64);
    u32 a3 = (u32)__shfl((int)p0.y, s1, 64);
    u32 b0 = (u32)__shfl((int)p1.x, s0, 64);
    u32 b1 = (u32)__shfl((int)p1.y, s0, 64);
    u32 b2 = (u32)__shfl((int)p1.x, s1, 64);
    u32 b3 = (u32)__shfl((int)p1.y, s1, 64);
    const bool hi = (kg >= 2);
    union { u32 u[4]; bf16x8 v; } r;
    r.u[0] = hi ? b0 : a0; r.u[1] = hi ? b1 : a1;
    r.u[2] = hi ? b2 : a2; r.u[3] = hi ? b3 : a3;
    return r.v;
}

// ws layout (u16 units):
//   [0,      196608)  W rows (Wq 0-255, Wk 256-511, Wv 512-767) row-major
//   [196608, 262144)  Wproj rows
//   [262144, 263424)  rpe_pk: (j*8 + h)*32 + hd
//   [263424, 263680)  w1_pk:  h*32 + hd              (fallback path)
//   [263680, 267776)  w1full: 16x256, row h: w1[h] in cols [h*32,h*32+32), else 0
//   [267776, 333312)  WvT packed per head (fallback path)
//   [333312, +3840*8*2624)  pages: per (n,t,h): q_pk 800 | ke_pk 800 | v_pk 1024
//   bias_ws (f32): 3840*256 at u16 index 80942592
#define PG_OFF_ 333312
#define NPAGES_ ((size_t)3840*8*2624)     // 80,609,280 u16
#define BIAS_U16_ (PG_OFF_ + NPAGES_)     // 80,942,592

__global__ void prep_kernel(const float* __restrict__ Wkv, const float* __restrict__ Wq,
                            const float* __restrict__ Wproj, const float* __restrict__ rpe,
                            const float* __restrict__ w1, u16* __restrict__ wpk)
{
    int i = blockIdx.x * 256 + threadIdx.x;
    if (i < 65536)        wpk[i] = f2bf(Wq[i]);
    else if (i < 196608)  wpk[i] = f2bf(Wkv[i - 65536]);
    else if (i < 262144)  wpk[i] = f2bf(Wproj[i - 196608]);
    else if (i < 263424){
        int j = i - 262144;
        int jj = j >> 8, h = (j >> 5) & 7, hd = j & 31;
        wpk[i] = f2bf(rpe[jj*256 + h*32 + hd]);
    }
    else if (i < 263680)  wpk[i] = f2bf(w1[i - 263424]);
    else if (i < 267776){
        int j = i - 263680;
        int r = j >> 8, c = j & 255;
        float v = (r < 8 && (c >> 5) == r) ? w1[r*32 + (c & 31)] : 0.f;
        wpk[i] = f2bf(v);
    }
    else if (i < 333312){
        int j = i - 267776;
        int h = j >> 13;
        int r = j & 8191;
        int coct = r >> 8, hd = (r >> 3) & 31, clo = r & 7;
        wpk[i] = f2bf(Wkv[(size_t)(256 + h*32 + hd) * 256 + coct*8 + clo]);
    }
}

// ============ kernel 1: batched GEMM  C[768][96000] = W @ X  ================
// R13 configuration (empirical optimum over 11 structural variants):
// grid 2880 = sec(3) x 960 col-tiles of 100, 512 thr / 8 waves, each wave
// 32 rows x 100 cols, K=256. Transpose-gather staging (conflict-free b128
// writes); L2 absorbs the 3x cross-sec X re-reads. No launch-bounds hint
// (hints either can't materialize at 51.7KB LDS or squeeze VGPR -> spills).
__launch_bounds__(512)
__global__ void qkv_gemm(const float* __restrict__ x, const float* __restrict__ e,
                         const u16* __restrict__ wpk, u16* __restrict__ pages,
                         float* __restrict__ bias_ws)
{
    __shared__ __align__(16) u16 xt[25664];   // [c>>3][col 100][c&7] + overrun pad

    const int tid = threadIdx.x;
    const int w = tid >> 6, lane = tid & 63;
    const int l15 = lane & 15, kg = lane >> 4;
    const int wg = ((int)blockIdx.x & 7) * 360 + ((int)blockIdx.x >> 3);  // XCD swizzle
    const int sec = wg / 960, cb = wg % 960;
    const int n = cb / 30, tg = cb % 30;
    const f32x4 zf = {0.f, 0.f, 0.f, 0.f};

    const float* xb = x + (size_t)n*768000 + tg*100;
    for (int i = tid; i < 3200; i += 512){
        int col = i % 100, coct = i / 100;
        const float* xc = xb + (size_t)(coct*8)*3000 + col;
        u32 p[4];
        #pragma unroll
        for (int r = 0; r < 4; ++r)
            p[r] = pk2(xc[(2*r)*3000], xc[(2*r+1)*3000]);
        *(uint4*)&xt[(coct*100 + col)*8] = *(const uint4*)p;
    }
    __syncthreads();

    f32x4 acc[2][8];
    #pragma unroll
    for (int m = 0; m < 2; ++m)
        #pragma unroll
        for (int f = 0; f < 8; ++f) acc[m][f] = zf;

    const u16* wrow = wpk + (size_t)(sec*256 + w*32 + l15) * 256;
    #pragma unroll
    for (int ks = 0; ks < 8; ++ks){
        bf16x8 a0 = *(const bf16x8*)(wrow + ks*32 + kg*8);
        bf16x8 a1 = *(const bf16x8*)(wrow + 4096 + ks*32 + kg*8);
        #pragma unroll
        for (int f = 0; f < 8; ++f){
            int col = (f>>1)*25 + (f&1)*16 + l15;
            bf16x8 b = *(const bf16x8*)&xt[((ks*4+kg)*100 + col)*8];
            acc[0][f] = MFMA(a0, b, acc[0][f]);
            acc[1][f] = MFMA(a1, b, acc[1][f]);
        }
    }

    if (sec == 1){
        __syncthreads();
        const float* ebp = e + (size_t)n*768000 + tg*100;
        for (int i = tid; i < 3200; i += 512){
            int col = i % 100, coct = i / 100;
            const float* ec = ebp + (size_t)(coct*8)*3000 + col;
            u32 p[4];
            #pragma unroll
            for (int r = 0; r < 4; ++r)
                p[r] = pk2(ec[(2*r)*3000], ec[(2*r+1)*3000]);
            *(uint4*)&xt[(coct*100 + col)*8] = *(const uint4*)p;
        }
        __syncthreads();
        #pragma unroll
        for (int m = 0; m < 2; ++m){
            int c0 = w*32 + m*16 + kg*4;
            #pragma unroll
            for (int f = 0; f < 8; ++f){
                int col = (f>>1)*25 + (f&1)*16 + l15;
                uint2 ev = *(const uint2*)&xt[((c0>>3)*100 + col)*8 + (c0&7)];
                acc[m][f][0] += bf2f(ev.x & 0xFFFFu);
                acc[m][f][1] += bf2f(ev.x >> 16);
                acc[m][f][2] += bf2f(ev.y & 0xFFFFu);
                acc[m][f][3] += bf2f(ev.y >> 16);
            }
        }
    }

    // write packed pages
    const int secoff = (sec == 0) ? 0 : (sec == 1 ? 800 : 1600);
    #pragma unroll
    for (int m = 0; m < 2; ++m){
        #pragma unroll
        for (int f = 0; f < 8; ++f){
            int tt = f >> 1, a = (f&1)*16 + l15;
            if (a < 25){
                size_t nt = (size_t)(n*120 + tg*4 + tt);
                u16* pg = pages + (nt*8 + w)*2624 + secoff;
                int hd0 = m*16 + kg*4;
                if (sec < 2){
                    uint2 val; val.x = pk2(acc[m][f][0], acc[m][f][1]);
                    val.y = pk2(acc[m][f][2], acc[m][f][3]);
                    *(uint2*)&pg[((hd0>>3)*25 + a)*8 + (hd0&7)] = val;
                } else {
                    #pragma unroll
                    for (int r = 0; r < 4; ++r)
                        pg[((a>>3)*32 + hd0 + r)*8 + (a&7)] = f2bf(acc[m][f][r]);
                }
            }
        }
    }

    // bias = w1full @ E  (wave 0 of sec==1 blocks; E still in LDS)
    if (sec == 1 && w == 0){
        f32x4 bacc[8];
        #pragma unroll
        for (int f = 0; f < 8; ++f) bacc[f] = zf;
        const u16* w1f = wpk + 263680 + l15*256;
        #pragma unroll
        for (int ks = 0; ks < 8; ++ks){
            bf16x8 a = *(const bf16x8*)(w1f + ks*32 + kg*8);
            #pragma unroll
            for (int f = 0; f < 8; ++f){
                int col = (f>>1)*25 + (f&1)*16 + l15;
                bf16x8 b = *(const bf16x8*)&xt[((ks*4+kg)*100 + col)*8];
                bacc[f] = MFMA(a, b, bacc[f]);
            }
        }
        if (kg < 2){
            #pragma unroll
            for (int f = 0; f < 8; ++f){
                int tt = f >> 1, a = (f&1)*16 + l15;
                if (a < 25){
                    int nt = n*120 + tg*4 + tt;
                    #pragma unroll
                    for (int r = 0; r < 4; ++r)
                        bias_ws[(size_t)nt*256 + (kg*4+r)*32 + a] = bacc[f][r];
                }
            }
        }
    }
}

// ============ kernel 2: attention + proj, reading packed pages ==============
// Per (n,t): 8 waves = 8 heads. q/ke/v fragments = single b128 global loads.
__launch_bounds__(512)
__global__ void attn_proj(const float* __restrict__ outer, const float* __restrict__ alpha,
                          const float* __restrict__ bproj, const u16* __restrict__ wpk,
                          const u16* __restrict__ pages, const float* __restrict__ bias_ws,
                          float* __restrict__ out)
{
    __shared__ __align__(16) u16 opk[6656 + 64];

    const int tid = threadIdx.x;
    const int w = tid >> 6, lane = tid & 63;
    const int l15 = lane & 15, kg = lane >> 4;
    const int wg = ((int)blockIdx.x & 7) * 480 + ((int)blockIdx.x >> 3);
    const int n = wg / 120, t = wg % 120;
    const float alpha0 = alpha[0];
    const f32x4 zf = {0.f, 0.f, 0.f, 0.f};
    const int h = w;
    const u16* pg = pages + ((size_t)wg*8 + h)*2624;

    // ===== fragments straight from pages =====
    bf16x8 fq0  = *(const bf16x8*)&pg[(kg*25 + l15)*8];
    bf16x8 fq1  = *(const bf16x8*)&pg[(kg*25 + 16 + l15)*8];
    bf16x8 fke0 = *(const bf16x8*)&pg[800 + (kg*25 + l15)*8];
    bf16x8 fke1;
    if (l15 < 9)       fke1 = *(const bf16x8*)&pg[800 + (kg*25 + 16 + l15)*8];
    else if (l15 <= 13) fke1 = *(const bf16x8*)(wpk + 262144 + ((l15-9)*8 + h)*32 + kg*8);
    else { union { u32 u[4]; bf16x8 v; } z; z.u[0]=z.u[1]=z.u[2]=z.u[3]=0; fke1 = z.v; }

    f32x4 sc[2][2];
    sc[0][0] = MFMA(fke0, fq0, zf);
    sc[0][1] = MFMA(fke0, fq1, zf);
    sc[1][0] = MFMA(fke1, fq0, zf);
    sc[1][1] = MFMA(fke1, fq1, zf);

    float bias01[2];
    bias01[0] = bias_ws[(size_t)wg*256 + h*32 + l15];
    bias01[1] = bias_ws[(size_t)wg*256 + h*32 + 16 + l15];

    // ===== softmax over b (per column a), fuse alpha*P + outer =====
    uint2 P_G[2][2];
    #pragma unroll
    for (int nt = 0; nt < 2; ++nt){
        const int a = nt*16 + l15;
        f32x4 s0 = sc[0][nt], s1 = sc[1][nt];
        float rr0 = __shfl(s1[1], 32 + l15, 64);
        float rr1 = __shfl(s1[2], 32 + l15, 64);
        float rr2 = __shfl(s1[3], 32 + l15, 64);
        float rr3 = __shfl(s1[0], 48 + l15, 64);
        float rr4 = __shfl(s1[1], 48 + l15, 64);
        float tv[8];
        #pragma unroll
        for (int mt = 0; mt < 2; ++mt)
            #pragma unroll
            for (int r = 0; r < 4; ++r){
                int b = mt*16 + kg*4 + r;
                float sval = mt ? s1[r] : s0[r];
                float bb = __shfl(bias01[mt], (lane & 48) + (b & 15), 64);
                int d = a - b; d = d < 0 ? -d : d; if (d > 4) d = 4;
                float rj = d==0?rr0 : d==1?rr1 : d==2?rr2 : d==3?rr3 : rr4;
                float tt = (sval + rj + bb) * SCALE_;
                tv[mt*4+r] = (b < 25) ? tt : -1e30f;
            }
        float m = tv[0];
        #pragma unroll
        for (int i = 1; i < 8; ++i) m = fmaxf(m, tv[i]);
        m = fmaxf(m, __shfl_xor(m, 16, 64));
        m = fmaxf(m, __shfl_xor(m, 32, 64));
        float ex[8], sm = 0.f;
        #pragma unroll
        for (int i = 0; i < 8; ++i){ ex[i] = __expf(tv[i] - m); sm += ex[i]; }
        sm += __shfl_xor(sm, 16, 64);
        sm += __shfl_xor(sm, 32, 64);
        const float inv = alpha0 / sm;
        float g[8];
        #pragma unroll
        for (int mt = 0; mt < 2; ++mt)
            #pragma unroll
            for (int r = 0; r < 4; ++r){
                int b = mt*16 + kg*4 + r;
                float ov = (a < 25 && b < 25) ? outer[((size_t)h*25 + a)*25 + b] : 0.f;
                g[mt*4+r] = (b < 25) ? ex[mt*4+r]*inv + ov : 0.f;
            }
        uint2 pg0; pg0.x = pk2(g[0], g[1]); pg0.y = pk2(g[2], g[3]);
        uint2 pg1; pg1.x = pk2(g[4], g[5]); pg1.y = pk2(g[6], g[7]);
        P_G[nt][0] = pg0; P_G[nt][1] = pg1;
    }

    // ===== PV: C[hd][a] = v^T[hd][b] @ G^T[b][a] =====
    {
        bf16x8 fv0 = *(const bf16x8*)&pg[1600 + (kg*32 + l15)*8];
        bf16x8 fv1 = *(const bf16x8*)&pg[1600 + (kg*32 + 16 + l15)*8];
        bf16x8 fg0 = frag8(P_G[0][0], P_G[0][1], kg, l15);
        bf16x8 fg1 = frag8(P_G[1][0], P_G[1][1], kg, l15);
        f32x4 o[2][2];
        o[0][0] = MFMA(fv0, fg0, zf); o[0][1] = MFMA(fv0, fg1, zf);
        o[1][0] = MFMA(fv1, fg0, zf); o[1][1] = MFMA(fv1, fg1, zf);
        #pragma unroll
        for (int mt = 0; mt < 2; ++mt)
            #pragma unroll
            for (int nt = 0; nt < 2; ++nt){
                int a = nt*16 + l15;
                if (a < 25){
                    int coct = h*4 + mt*2 + (kg>>1);
                    u32* dst = (u32*)&opk[(coct*26 + a)*8 + (kg&1)*4];
                    dst[0] = pk2(o[mt][nt][0], o[mt][nt][1]);
                    dst[1] = pk2(o[mt][nt][2], o[mt][nt][3]);
                }
            }
    }
    __syncthreads();

    // ===== proj: out = Wproj @ o + bproj, cooperative =====
    {
        f32x4 pc[2][2];
        #pragma unroll
        for (int i = 0; i < 2; ++i){ pc[i][0] = zf; pc[i][1] = zf; }
        #pragma unroll
        for (int ks = 0; ks < 8; ++ks){
            bf16x8 pb0 = *(const bf16x8*)&opk[((ks*4+kg)*26 + l15)*8];
            bf16x8 pb1 = *(const bf16x8*)&opk[((ks*4+kg)*26 + 16 + l15)*8];
            #pragma unroll
            for (int i = 0; i < 2; ++i){
                bf16x8 aw = *(const bf16x8*)(wpk + 196608 +
                                (size_t)(w*32 + i*16 + l15)*256 + ks*32 + kg*8);
                pc[i][0] = MFMA(aw, pb0, pc[i][0]);
                pc[i][1] = MFMA(aw, pb1, pc[i][1]);
            }
        }
        #pragma unroll
        for (int i = 0; i < 2; ++i){
            const int d = w*32 + i*16 + kg*4;
            float b0 = bproj[d], b1 = bproj[d+1], b2 = bproj[d+2], b3 = bproj[d+3];
            #pragma unroll
            for (int nt = 0; nt < 2; ++nt){
                int v = nt*16 + l15;
                if (v < 25){
                    float* op = out + (size_t)n*768000 + (size_t)d*3000 + t*25 + v;
                    op[0]    = pc[i][nt][0] + b0;
                    op[3000] = pc[i][nt][1] + b1;
                    op[6000] = pc[i][nt][2] + b2;
                    op[9000] = pc[i][nt][3] + b3;
                }
            }
        }
    }
}

// ============== FALLBACK: fused kernel (R7, 303us) ==========================
__launch_bounds__(512, 4)
__global__ void mhsa_main(const float* __restrict__ x, const float* __restrict__ e,
                          const float* __restrict__ outer, const float* __restrict__ alpha,
                          const float* __restrict__ bproj, const u16* __restrict__ wpk,
                          float* __restrict__ out)
{
    __shared__ __align__(16) u16 smem[6656*3 + 64];
    u16* xs  = smem;
    u16* es  = smem + 6656;
    u16* opk = smem + 13312;

    const int tid = threadIdx.x;
    const int w = tid >> 6, lane = tid & 63;
    const int l15 = lane & 15, kg = lane >> 4;
    const int wg = (blockIdx.x & 7) * 480 + (blockIdx.x >> 3);
    const int n = wg / 120, t = wg % 120;
    const float alpha0 = alpha[0];
    const f32x4 zf = {0.f, 0.f, 0.f, 0.f};

    const float* xb = x + (size_t)n*768000 + t*25;
    const float* eb = e + (size_t)n*768000 + t*25;
    for (int i = tid; i < 6400; i += 512){
        int c = i / 25, v = i - c*25;
        int a16 = ((c>>3)*26 + v)*8 + (c&7);
        xs[a16] = f2bf(xb[c*3000 + v]);
        es[a16] = f2bf(eb[c*3000 + v]);
    }
    __syncthreads();

    {
        const int h = w;
        f32x4 cq[2][2], ck[2][2];
        #pragma unroll
        for (int i = 0; i < 2; ++i)
            #pragma unroll
            for (int j = 0; j < 2; ++j){ cq[i][j] = zf; ck[i][j] = zf; }
        {
            const u16* wq0 = wpk + (size_t)(h*32 + l15)*256;
            const u16* wk0 = wpk + 65536 + (size_t)(h*32 + l15)*256;
            #pragma unroll
            for (int ks = 0; ks < 8; ++ks){
                bf16x8 b0 = *(const bf16x8*)&xs[((ks*4+kg)*26 + l15)*8];
                bf16x8 b1 = *(const bf16x8*)&xs[((ks*4+kg)*26 + 16 + l15)*8];
                bf16x8 aq0 = *(const bf16x8*)(wq0 + ks*32 + kg*8);
                bf16x8 aq1 = *(const bf16x8*)(wq0 + 4096 + ks*32 + kg*8);
                bf16x8 ak0 = *(const bf16x8*)(wk0 + ks*32 + kg*8);
                bf16x8 ak1 = *(const bf16x8*)(wk0 + 4096 + ks*32 + kg*8);
                cq[0][0]=MFMA(aq0,b0,cq[0][0]); cq[0][1]=MFMA(aq0,b1,cq[0][1]);
                cq[1][0]=MFMA(aq1,b0,cq[1][0]); cq[1][1]=MFMA(aq1,b1,cq[1][1]);
                ck[0][0]=MFMA(ak0,b0,ck[0][0]); ck[0][1]=MFMA(ak0,b1,ck[0][1]);
                ck[1][0]=MFMA(ak1,b0,ck[1][0]); ck[1][1]=MFMA(ak1,b1,ck[1][1]);
            }
        }
        uint2 P_q[2][2], P_k[2][2];
        #pragma unroll
        for (int mt = 0; mt < 2; ++mt)
            #pragma unroll
            for (int nt = 0; nt < 2; ++nt){
                int coct = h*4 + mt*2 + (kg>>1);
                uint2 ev = *(const uint2*)&es[(coct*26 + nt*16 + l15)*8 + (kg&1)*4];
                ck[mt][nt][0] += bf2f(ev.x & 0xFFFFu);
                ck[mt][nt][1] += bf2f(ev.x >> 16);
                ck[mt][nt][2] += bf2f(ev.y & 0xFFFFu);
                ck[mt][nt][3] += bf2f(ev.y >> 16);
                uint2 pq; pq.x = pk2(cq[mt][nt][0], cq[mt][nt][1]);
                pq.y = pk2(cq[mt][nt][2], cq[mt][nt][3]);
                P_q[nt][mt] = pq;
                uint2 pk; pk.x = pk2(ck[mt][nt][0], ck[mt][nt][1]);
                pk.y = pk2(ck[mt][nt][2], ck[mt][nt][3]);
                P_k[nt][mt] = pk;
            }
        float bias01[2];
        {
            bf16x8 aw1 = *(const bf16x8*)(wpk + 263424 + h*32 + kg*8);
            bf16x8 be0 = *(const bf16x8*)&es[((h*4+kg)*26 + l15)*8];
            bf16x8 be1 = *(const bf16x8*)&es[((h*4+kg)*26 + 16 + l15)*8];
            f32x4 cb0 = MFMA(aw1, be0, zf);
            f32x4 cb1 = MFMA(aw1, be1, zf);
            bias01[0] = cb0[0]; bias01[1] = cb1[0];
        }
        f32x4 cv[2][2];
        #pragma unroll
        for (int i = 0; i < 2; ++i)
            #pragma unroll
            for (int j = 0; j < 2; ++j) cv[i][j] = zf;
        {
            const u16* wvt = wpk + 267776 + h*8192;
            #pragma unroll
            for (int ks = 0; ks < 8; ++ks){
                bf16x8 a0 = *(const bf16x8*)&xs[((ks*4+kg)*26 + l15)*8];
                bf16x8 a1 = *(const bf16x8*)&xs[((ks*4+kg)*26 + 16 + l15)*8];
                bf16x8 bv0 = *(const bf16x8*)&wvt[((ks*4+kg)*32 + l15)*8];
                bf16x8 bv1 = *(const bf16x8*)&wvt[((ks*4+kg)*32 + 16 + l15)*8];
                cv[0][0]=MFMA(a0,bv0,cv[0][0]); cv[0][1]=MFMA(a0,bv1,cv[0][1]);
                cv[1][0]=MFMA(a1,bv0,cv[1][0]); cv[1][1]=MFMA(a1,bv1,cv[1][1]);
            }
        }
        #pragma unroll
        for (int nt = 0; nt < 2; ++nt)
            #pragma unroll
            for (int r = 0; r < 4; ++r)
                cv[1][nt][r] = (kg*4 + r < 9) ? cv[1][nt][r] : 0.f;
        uint2 P_v[2][2];
        #pragma unroll
        for (int mt = 0; mt < 2; ++mt)
            #pragma unroll
            for (int nt = 0; nt < 2; ++nt){
                uint2 pv; pv.x = pk2(cv[mt][nt][0], cv[mt][nt][1]);
                pv.y = pk2(cv[mt][nt][2], cv[mt][nt][3]);
                P_v[nt][mt] = pv;
            }
        bf16x8 fq0  = frag8(P_q[0][0], P_q[0][1], kg, l15);
        bf16x8 fq1  = frag8(P_q[1][0], P_q[1][1], kg, l15);
        bf16x8 fke0 = frag8(P_k[0][0], P_k[0][1], kg, l15);
        bf16x8 fke1 = frag8(P_k[1][0], P_k[1][1], kg, l15);
        if (l15 >= 9){
            if (l15 <= 13)
                fke1 = *(const bf16x8*)(wpk + 262144 + ((l15-9)*8 + h)*32 + kg*8);
            else {
                union { u32 u[4]; bf16x8 v; } z; z.u[0]=z.u[1]=z.u[2]=z.u[3]=0;
                fke1 = z.v;
            }
        }
        f32x4 sc[2][2];
        sc[0][0] = MFMA(fke0, fq0, zf);
        sc[0][1] = MFMA(fke0, fq1, zf);
        sc[1][0] = MFMA(fke1, fq0, zf);
        sc[1][1] = MFMA(fke1, fq1, zf);
        uint2 P_G[2][2];
        #pragma unroll
        for (int nt = 0; nt < 2; ++nt){
            const int a = nt*16 + l15;
            f32x4 s0 = sc[0][nt], s1 = sc[1][nt];
            float rr0 = __shfl(s1[1], 32 + l15, 64);
            float rr1 = __shfl(s1[2], 32 + l15, 64);
            float rr2 = __shfl(s1[3], 32 + l15, 64);
            float rr3 = __shfl(s1[0], 48 + l15, 64);
            float rr4 = __shfl(s1[1], 48 + l15, 64);
            float tv[8];
            #pragma unroll
            for (int mt = 0; mt < 2; ++mt)
                #pragma unroll
                for (int r = 0; r < 4; ++r){
                    int b = mt*16 + kg*4 + r;
                    float sval = mt ? s1[r] : s0[r];
                    float bb = __shfl(bias01[mt], (lane & 48) + (b & 15), 64);
                    int d = a - b; d = d < 0 ? -d : d; if (d > 4) d = 4;
                    float rj = d==0?rr0 : d==1?rr1 : d==2?rr2 : d==3?rr3 : rr4;
                    float tt = (sval + rj + bb) * SCALE_;
                    tv[mt*4+r] = (b < 25) ? tt : -1e30f;
                }
            float m = tv[0];
            #pragma unroll
            for (int i = 1; i < 8; ++i) m = fmaxf(m, tv[i]);
            m = fmaxf(m, __shfl_xor(m, 16, 64));
            m = fmaxf(m, __shfl_xor(m, 32, 64));
            float ex[8], sm = 0.f;
            #pragma unroll
            for (int i = 0; i < 8; ++i){ ex[i] = __expf(tv[i] - m); sm += ex[i]; }
            sm += __shfl_xor(sm, 16, 64);
            sm += __shfl_xor(sm, 32, 64);
            const float inv = alpha0 / sm;
            float g[8];
            #pragma unroll
            for (int mt = 0; mt < 2; ++mt)
                #pragma unroll
                for (int r = 0; r < 4; ++r){
                    int b = mt*16 + kg*4 + r;
                    float ov = (a < 25 && b < 25) ? outer[((size_t)h*25 + a)*25 + b] : 0.f;
                    g[mt*4+r] = (b < 25) ? ex[mt*4+r]*inv + ov : 0.f;
                }
            uint2 pg0; pg0.x = pk2(g[0], g[1]); pg0.y = pk2(g[2], g[3]);
            uint2 pg1; pg1.x = pk2(g[4], g[5]); pg1.y = pk2(g[6], g[7]);
            P_G[nt][0] = pg0; P_G[nt][1] = pg1;
        }
        {
            bf16x8 fv0 = frag8(P_v[0][0], P_v[0][1], kg, l15);
            bf16x8 fv1 = frag8(P_v[1][0], P_v[1][1], kg, l15);
            bf16x8 fg0 = frag8(P_G[0][0], P_G[0][1], kg, l15);
            bf16x8 fg1 = frag8(P_G[1][0], P_G[1][1], kg, l15);
            f32x4 o[2][2];
            o[0][0] = MFMA(fv0, fg0, zf); o[0][1] = MFMA(fv0, fg1, zf);
            o[1][0] = MFMA(fv1, fg0, zf); o[1][1] = MFMA(fv1, fg1, zf);
            #pragma unroll
            for (int mt = 0; mt < 2; ++mt)
                #pragma unroll
                for (int nt = 0; nt < 2; ++nt){
                    int a = nt*16 + l15;
                    if (a < 25){
                        int coct = h*4 + mt*2 + (kg>>1);
                        u32* dst = (u32*)&opk[(coct*26 + a)*8 + (kg&1)*4];
                        dst[0] = pk2(o[mt][nt][0], o[mt][nt][1]);
                        dst[1] = pk2(o[mt][nt][2], o[mt][nt][3]);
                    }
                }
        }
    }
    __syncthreads();

    {
        f32x4 pc[2][2];
        #pragma unroll
        for (int i = 0; i < 2; ++i){ pc[i][0] = zf; pc[i][1] = zf; }
        #pragma unroll
        for (int ks = 0; ks < 8; ++ks){
            bf16x8 pb0 = *(const bf16x8*)&opk[((ks*4+kg)*26 + l15)*8];
            bf16x8 pb1 = *(const bf16x8*)&opk[((ks*4+kg)*26 + 16 + l15)*8];
            #pragma unroll
            for (int i = 0; i < 2; ++i){
                bf16x8 aw = *(const bf16x8*)(wpk + 196608 +
                                (size_t)(w*32 + i*16 + l15)*256 + ks*32 + kg*8);
                pc[i][0] = MFMA(aw, pb0, pc[i][0]);
                pc[i][1] = MFMA(aw, pb1, pc[i][1]);
            }
        }
        #pragma unroll
        for (int i = 0; i < 2; ++i){
            const int d = w*32 + i*16 + kg*4;
            float b0 = bproj[d], b1 = bproj[d+1], b2 = bproj[d+2], b3 = bproj[d+3];
            #pragma unroll
            for (int nt = 0; nt < 2; ++nt){
                int v = nt*16 + l15;
                if (v < 25){
                    float* op = out + (size_t)n*768000 + (size_t)d*3000 + t*25 + v;
                    op[0]    = pc[i][nt][0] + b0;
                    op[3000] = pc[i][nt][1] + b1;
                    op[6000] = pc[i][nt][2] + b2;
                    op[9000] = pc[i][nt][3] + b3;
                }
            }
        }
    }
}

extern "C" void kernel_launch(void* const* d_in, const int* in_sizes, int n_in,
                              void* d_out, int out_size, void* d_ws, size_t ws_size,
                              hipStream_t stream) {
    (void)in_sizes; (void)n_in; (void)out_size;
    const float* x     = (const float*)d_in[0];
    const float* e     = (const float*)d_in[1];
    const float* Wkv   = (const float*)d_in[2];
    const float* Wq    = (const float*)d_in[3];
    const float* Wproj = (const float*)d_in[4];
    const float* bproj = (const float*)d_in[5];
    const float* rpe   = (const float*)d_in[6];
    const float* w1    = (const float*)d_in[7];
    const float* outer = (const float*)d_in[8];
    const float* alpha = (const float*)d_in[9];
    float* out = (float*)d_out;
    u16* wpk = (u16*)d_ws;

    prep_kernel<<<1302, 256, 0, stream>>>(Wkv, Wq, Wproj, rpe, w1, wpk);

    const size_t need = (size_t)BIAS_U16_ * 2 + (size_t)3840*256*4 + 4096;  // ~165.8 MB
    if (ws_size >= need){
        u16* pages = wpk + PG_OFF_;
        float* bias_ws = (float*)(wpk + BIAS_U16_);
        qkv_gemm<<<2880, 512, 0, stream>>>(x, e, wpk, pages, bias_ws);
        attn_proj<<<3840, 512, 0, stream>>>(outer, alpha, bproj, wpk, pages, bias_ws, out);
    } else {
        mhsa_main<<<3840, 512, 0, stream>>>(x, e, outer, alpha, bproj, wpk, out);
    }
}

// Round 20
// 274.208 us; speedup vs baseline: 1.2399x; 1.0155x over previous
//
#include <hip/hip_runtime.h>

typedef __attribute__((ext_vector_type(8))) short bf16x8;
typedef __attribute__((ext_vector_type(4))) float f32x4;
typedef unsigned short u16;
typedef unsigned int u32;

#define SCALE_ 0.17677669529663687f   // 32^-0.5
#define MFMA(a,b,c) __builtin_amdgcn_mfma_f32_16x16x32_bf16(a,b,c,0,0,0)

__device__ __forceinline__ u16 f2bf(float f){
    u32 u = __float_as_uint(f);
    u = (u + 0x7FFFu + ((u >> 16) & 1u)) >> 16;
    return (u16)u;
}
__device__ __forceinline__ float bf2f(u32 h){ return __uint_as_float(h << 16); }
__device__ __forceinline__ u32 pk2(float a, float b){ return (u32)f2bf(a) | ((u32)f2bf(b) << 16); }

// Build an 8-element (K-octet) MFMA fragment from packed C-tiles via shuffles.
__device__ __forceinline__ bf16x8 frag8(uint2 p0, uint2 p1, int kg, int l15){
    const int s0 = ((kg & 1) << 5) + l15;
    const int s1 = s0 + 16;
    u32 a0 = (u32)__shfl((int)p0.x, s0, 64);
    u32 a1 = (u32)__shfl((int)p0.y, s0, 64);
    u32 a2 = (u32)__shfl((int)p0.x, s1, 64);
    u32 a3 = (u32)__shfl((int)p0.y, s1, 64);
    u32 b0 = (u32)__shfl((int)p1.x, s0, 64);
    u32 b1 = (u32)__shfl((int)p1.y, s0, 64);
    u32 b2 = (u32)__shfl((int)p1.x, s1, 64);
    u32 b3 = (u32)__shfl((int)p1.y, s1, 64);
    const bool hi = (kg >= 2);
    union { u32 u[4]; bf16x8 v; } r;
    r.u[0] = hi ? b0 : a0; r.u[1] = hi ? b1 : a1;
    r.u[2] = hi ? b2 : a2; r.u[3] = hi ? b3 : a3;
    return r.v;
}

// ws layout (u16 units):
//   [0,      196608)  W rows (Wq 0-255, Wk 256-511, Wv 512-767) row-major
//   [196608, 262144)  Wproj rows
//   [262144, 263424)  rpe_pk: (j*8 + h)*32 + hd
//   [263424, 263680)  w1_pk:  h*32 + hd              (fallback path)
//   [263680, 267776)  w1full: 16x256, row h: w1[h] in cols [h*32,h*32+32), else 0
//   [267776, 333312)  WvT packed per head (fallback path)
//   [333312, +3840*8*2624)  pages: per (n,t,h): q_pk 800 | ke_pk 800 | v_pk 1024
//   bias_ws (f32): 3840*256 at u16 index 80942592
#define PG_OFF_ 333312
#define NPAGES_ ((size_t)3840*8*2624)     // 80,609,280 u16
#define BIAS_U16_ (PG_OFF_ + NPAGES_)     // 80,942,592

__global__ void prep_kernel(const float* __restrict__ Wkv, const float* __restrict__ Wq,
                            const float* __restrict__ Wproj, const float* __restrict__ rpe,
                            const float* __restrict__ w1, u16* __restrict__ wpk)
{
    int i = blockIdx.x * 256 + threadIdx.x;
    if (i < 65536)        wpk[i] = f2bf(Wq[i]);
    else if (i < 196608)  wpk[i] = f2bf(Wkv[i - 65536]);
    else if (i < 262144)  wpk[i] = f2bf(Wproj[i - 196608]);
    else if (i < 263424){
        int j = i - 262144;
        int jj = j >> 8, h = (j >> 5) & 7, hd = j & 31;
        wpk[i] = f2bf(rpe[jj*256 + h*32 + hd]);
    }
    else if (i < 263680)  wpk[i] = f2bf(w1[i - 263424]);
    else if (i < 267776){
        int j = i - 263680;
        int r = j >> 8, c = j & 255;
        float v = (r < 8 && (c >> 5) == r) ? w1[r*32 + (c & 31)] : 0.f;
        wpk[i] = f2bf(v);
    }
    else if (i < 333312){
        int j = i - 267776;
        int h = j >> 13;
        int r = j & 8191;
        int coct = r >> 8, hd = (r >> 3) & 31, clo = r & 7;
        wpk[i] = f2bf(Wkv[(size_t)(256 + h*32 + hd) * 256 + coct*8 + clo]);
    }
}

// ============ kernel 1: batched GEMM  C[768][96000] = W @ X  ================
// R13 structure (empirical optimum): grid 2880 = sec(3) x 960 col-tiles of
// 100, 512 thr / 8 waves, each wave 32 rows x 100 cols, K=256.
// R20 change: WIDE staging gather -- each thread owns 4 consecutive cols x
// one K-octet: 8x float4 coalesced loads + 4x b128 LDS writes, cutting the
// staging load-issue count 4x (R19 counters: ~115us of qkv is exposed load
// latency on the 50-dword/thread gather). Everything else identical.
__launch_bounds__(512)
__global__ void qkv_gemm(const float* __restrict__ x, const float* __restrict__ e,
                         const u16* __restrict__ wpk, u16* __restrict__ pages,
                         float* __restrict__ bias_ws)
{
    __shared__ __align__(16) u16 xt[25664];   // [c>>3][col 100][c&7] + overrun pad

    const int tid = threadIdx.x;
    const int w = tid >> 6, lane = tid & 63;
    const int l15 = lane & 15, kg = lane >> 4;
    const int wg = ((int)blockIdx.x & 7) * 360 + ((int)blockIdx.x >> 3);  // XCD swizzle
    const int sec = wg / 960, cb = wg % 960;
    const int n = cb / 30, tg = cb % 30;
    const f32x4 zf = {0.f, 0.f, 0.f, 0.f};

    // ---- stage X: thread = (coct, col-quad); 8 coalesced float4 loads ----
    const float* xb = x + (size_t)n*768000 + tg*100;
    for (int i = tid; i < 800; i += 512){
        int c4 = i % 25, coct = i / 25;
        const float* xc = xb + (size_t)(coct*8)*3000 + c4*4;
        u32 cell[4][4];
        #pragma unroll
        for (int r = 0; r < 8; r += 2){
            float4 v0 = *(const float4*)&xc[r*3000];
            float4 v1 = *(const float4*)&xc[(r+1)*3000];
            int idx = r >> 1;
            cell[0][idx] = pk2(v0.x, v1.x);
            cell[1][idx] = pk2(v0.y, v1.y);
            cell[2][idx] = pk2(v0.z, v1.z);
            cell[3][idx] = pk2(v0.w, v1.w);
        }
        #pragma unroll
        for (int c = 0; c < 4; ++c)
            *(uint4*)&xt[(coct*100 + c4*4 + c)*8] = *(const uint4*)cell[c];
    }
    __syncthreads();

    f32x4 acc[2][8];
    #pragma unroll
    for (int m = 0; m < 2; ++m)
        #pragma unroll
        for (int f = 0; f < 8; ++f) acc[m][f] = zf;

    const u16* wrow = wpk + (size_t)(sec*256 + w*32 + l15) * 256;
    #pragma unroll
    for (int ks = 0; ks < 8; ++ks){
        bf16x8 a0 = *(const bf16x8*)(wrow + ks*32 + kg*8);
        bf16x8 a1 = *(const bf16x8*)(wrow + 4096 + ks*32 + kg*8);
        #pragma unroll
        for (int f = 0; f < 8; ++f){
            int col = (f>>1)*25 + (f&1)*16 + l15;
            bf16x8 b = *(const bf16x8*)&xt[((ks*4+kg)*100 + col)*8];
            acc[0][f] = MFMA(a0, b, acc[0][f]);
            acc[1][f] = MFMA(a1, b, acc[1][f]);
        }
    }

    if (sec == 1){
        __syncthreads();
        const float* ebp = e + (size_t)n*768000 + tg*100;
        for (int i = tid; i < 800; i += 512){
            int c4 = i % 25, coct = i / 25;
            const float* ec = ebp + (size_t)(coct*8)*3000 + c4*4;
            u32 cell[4][4];
            #pragma unroll
            for (int r = 0; r < 8; r += 2){
                float4 v0 = *(const float4*)&ec[r*3000];
                float4 v1 = *(const float4*)&ec[(r+1)*3000];
                int idx = r >> 1;
                cell[0][idx] = pk2(v0.x, v1.x);
                cell[1][idx] = pk2(v0.y, v1.y);
                cell[2][idx] = pk2(v0.z, v1.z);
                cell[3][idx] = pk2(v0.w, v1.w);
            }
            #pragma unroll
            for (int c = 0; c < 4; ++c)
                *(uint4*)&xt[(coct*100 + c4*4 + c)*8] = *(const uint4*)cell[c];
        }
        __syncthreads();
        #pragma unroll
        for (int m = 0; m < 2; ++m){
            int c0 = w*32 + m*16 + kg*4;
            #pragma unroll
            for (int f = 0; f < 8; ++f){
                int col = (f>>1)*25 + (f&1)*16 + l15;
                uint2 ev = *(const uint2*)&xt[((c0>>3)*100 + col)*8 + (c0&7)];
                acc[m][f][0] += bf2f(ev.x & 0xFFFFu);
                acc[m][f][1] += bf2f(ev.x >> 16);
                acc[m][f][2] += bf2f(ev.y & 0xFFFFu);
                acc[m][f][3] += bf2f(ev.y >> 16);
            }
        }
    }

    // write packed pages
    const int secoff = (sec == 0) ? 0 : (sec == 1 ? 800 : 1600);
    #pragma unroll
    for (int m = 0; m < 2; ++m){
        #pragma unroll
        for (int f = 0; f < 8; ++f){
            int tt = f >> 1, a = (f&1)*16 + l15;
            if (a < 25){
                size_t nt = (size_t)(n*120 + tg*4 + tt);
                u16* pg = pages + (nt*8 + w)*2624 + secoff;
                int hd0 = m*16 + kg*4;
                if (sec < 2){
                    uint2 val; val.x = pk2(acc[m][f][0], acc[m][f][1]);
                    val.y = pk2(acc[m][f][2], acc[m][f][3]);
                    *(uint2*)&pg[((hd0>>3)*25 + a)*8 + (hd0&7)] = val;
                } else {
                    #pragma unroll
                    for (int r = 0; r < 4; ++r)
                        pg[((a>>3)*32 + hd0 + r)*8 + (a&7)] = f2bf(acc[m][f][r]);
                }
            }
        }
    }

    // bias = w1full @ E  (wave 0 of sec==1 blocks; E still in LDS)
    if (sec == 1 && w == 0){
        f32x4 bacc[8];
        #pragma unroll
        for (int f = 0; f < 8; ++f) bacc[f] = zf;
        const u16* w1f = wpk + 263680 + l15*256;
        #pragma unroll
        for (int ks = 0; ks < 8; ++ks){
            bf16x8 a = *(const bf16x8*)(w1f + ks*32 + kg*8);
            #pragma unroll
            for (int f = 0; f < 8; ++f){
                int col = (f>>1)*25 + (f&1)*16 + l15;
                bf16x8 b = *(const bf16x8*)&xt[((ks*4+kg)*100 + col)*8];
                bacc[f] = MFMA(a, b, bacc[f]);
            }
        }
        if (kg < 2){
            #pragma unroll
            for (int f = 0; f < 8; ++f){
                int tt = f >> 1, a = (f&1)*16 + l15;
                if (a < 25){
                    int nt = n*120 + tg*4 + tt;
                    #pragma unroll
                    for (int r = 0; r < 4; ++r)
                        bias_ws[(size_t)nt*256 + (kg*4+r)*32 + a] = bacc[f][r];
                }
            }
        }
    }
}

// ============ kernel 2: attention + proj, reading packed pages ==============
// Per (n,t): 8 waves = 8 heads. q/ke/v fragments = single b128 global loads.
__launch_bounds__(512)
__global__ void attn_proj(const float* __restrict__ outer, const float* __restrict__ alpha,
                          const float* __restrict__ bproj, const u16* __restrict__ wpk,
                          const u16* __restrict__ pages, const float* __restrict__ bias_ws,
                          float* __restrict__ out)
{
    __shared__ __align__(16) u16 opk[6656 + 64];

    const int tid = threadIdx.x;
    const int w = tid >> 6, lane = tid & 63;
    const int l15 = lane & 15, kg = lane >> 4;
    const int wg = ((int)blockIdx.x & 7) * 480 + ((int)blockIdx.x >> 3);
    const int n = wg / 120, t = wg % 120;
    const float alpha0 = alpha[0];
    const f32x4 zf = {0.f, 0.f, 0.f, 0.f};
    const int h = w;
    const u16* pg = pages + ((size_t)wg*8 + h)*2624;

    // ===== fragments straight from pages =====
    bf16x8 fq0  = *(const bf16x8*)&pg[(kg*25 + l15)*8];
    bf16x8 fq1  = *(const bf16x8*)&pg[(kg*25 + 16 + l15)*8];
    bf16x8 fke0 = *(const bf16x8*)&pg[800 + (kg*25 + l15)*8];
    bf16x8 fke1;
    if (l15 < 9)       fke1 = *(const bf16x8*)&pg[800 + (kg*25 + 16 + l15)*8];
    else if (l15 <= 13) fke1 = *(const bf16x8*)(wpk + 262144 + ((l15-9)*8 + h)*32 + kg*8);
    else { union { u32 u[4]; bf16x8 v; } z; z.u[0]=z.u[1]=z.u[2]=z.u[3]=0; fke1 = z.v; }

    f32x4 sc[2][2];
    sc[0][0] = MFMA(fke0, fq0, zf);
    sc[0][1] = MFMA(fke0, fq1, zf);
    sc[1][0] = MFMA(fke1, fq0, zf);
    sc[1][1] = MFMA(fke1, fq1, zf);

    float bias01[2];
    bias01[0] = bias_ws[(size_t)wg*256 + h*32 + l15];
    bias01[1] = bias_ws[(size_t)wg*256 + h*32 + 16 + l15];

    // ===== softmax over b (per column a), fuse alpha*P + outer =====
    uint2 P_G[2][2];
    #pragma unroll
    for (int nt = 0; nt < 2; ++nt){
        const int a = nt*16 + l15;
        f32x4 s0 = sc[0][nt], s1 = sc[1][nt];
        float rr0 = __shfl(s1[1], 32 + l15, 64);
        float rr1 = __shfl(s1[2], 32 + l15, 64);
        float rr2 = __shfl(s1[3], 32 + l15, 64);
        float rr3 = __shfl(s1[0], 48 + l15, 64);
        float rr4 = __shfl(s1[1], 48 + l15, 64);
        float tv[8];
        #pragma unroll
        for (int mt = 0; mt < 2; ++mt)
            #pragma unroll
            for (int r = 0; r < 4; ++r){
                int b = mt*16 + kg*4 + r;
                float sval = mt ? s1[r] : s0[r];
                float bb = __shfl(bias01[mt], (lane & 48) + (b & 15), 64);
                int d = a - b; d = d < 0 ? -d : d; if (d > 4) d = 4;
                float rj = d==0?rr0 : d==1?rr1 : d==2?rr2 : d==3?rr3 : rr4;
                float tt = (sval + rj + bb) * SCALE_;
                tv[mt*4+r] = (b < 25) ? tt : -1e30f;
            }
        float m = tv[0];
        #pragma unroll
        for (int i = 1; i < 8; ++i) m = fmaxf(m, tv[i]);
        m = fmaxf(m, __shfl_xor(m, 16, 64));
        m = fmaxf(m, __shfl_xor(m, 32, 64));
        float ex[8], sm = 0.f;
        #pragma unroll
        for (int i = 0; i < 8; ++i){ ex[i] = __expf(tv[i] - m); sm += ex[i]; }
        sm += __shfl_xor(sm, 16, 64);
        sm += __shfl_xor(sm, 32, 64);
        const float inv = alpha0 / sm;
        float g[8];
        #pragma unroll
        for (int mt = 0; mt < 2; ++mt)
            #pragma unroll
            for (int r = 0; r < 4; ++r){
                int b = mt*16 + kg*4 + r;
                float ov = (a < 25 && b < 25) ? outer[((size_t)h*25 + a)*25 + b] : 0.f;
                g[mt*4+r] = (b < 25) ? ex[mt*4+r]*inv + ov : 0.f;
            }
        uint2 pg0; pg0.x = pk2(g[0], g[1]); pg0.y = pk2(g[2], g[3]);
        uint2 pg1; pg1.x = pk2(g[4], g[5]); pg1.y = pk2(g[6], g[7]);
        P_G[nt][0] = pg0; P_G[nt][1] = pg1;
    }

    // ===== PV: C[hd][a] = v^T[hd][b] @ G^T[b][a] =====
    {
        bf16x8 fv0 = *(const bf16x8*)&pg[1600 + (kg*32 + l15)*8];
        bf16x8 fv1 = *(const bf16x8*)&pg[1600 + (kg*32 + 16 + l15)*8];
        bf16x8 fg0 = frag8(P_G[0][0], P_G[0][1], kg, l15);
        bf16x8 fg1 = frag8(P_G[1][0], P_G[1][1], kg, l15);
        f32x4 o[2][2];
        o[0][0] = MFMA(fv0, fg0, zf); o[0][1] = MFMA(fv0, fg1, zf);
        o[1][0] = MFMA(fv1, fg0, zf); o[1][1] = MFMA(fv1, fg1, zf);
        #pragma unroll
        for (int mt = 0; mt < 2; ++mt)
            #pragma unroll
            for (int nt = 0; nt < 2; ++nt){
                int a = nt*16 + l15;
                if (a < 25){
                    int coct = h*4 + mt*2 + (kg>>1);
                    u32* dst = (u32*)&opk[(coct*26 + a)*8 + (kg&1)*4];
                    dst[0] = pk2(o[mt][nt][0], o[mt][nt][1]);
                    dst[1] = pk2(o[mt][nt][2], o[mt][nt][3]);
                }
            }
    }
    __syncthreads();

    // ===== proj: out = Wproj @ o + bproj, cooperative =====
    {
        f32x4 pc[2][2];
        #pragma unroll
        for (int i = 0; i < 2; ++i){ pc[i][0] = zf; pc[i][1] = zf; }
        #pragma unroll
        for (int ks = 0; ks < 8; ++ks){
            bf16x8 pb0 = *(const bf16x8*)&opk[((ks*4+kg)*26 + l15)*8];
            bf16x8 pb1 = *(const bf16x8*)&opk[((ks*4+kg)*26 + 16 + l15)*8];
            #pragma unroll
            for (int i = 0; i < 2; ++i){
                bf16x8 aw = *(const bf16x8*)(wpk + 196608 +
                                (size_t)(w*32 + i*16 + l15)*256 + ks*32 + kg*8);
                pc[i][0] = MFMA(aw, pb0, pc[i][0]);
                pc[i][1] = MFMA(aw, pb1, pc[i][1]);
            }
        }
        #pragma unroll
        for (int i = 0; i < 2; ++i){
            const int d = w*32 + i*16 + kg*4;
            float b0 = bproj[d], b1 = bproj[d+1], b2 = bproj[d+2], b3 = bproj[d+3];
            #pragma unroll
            for (int nt = 0; nt < 2; ++nt){
                int v = nt*16 + l15;
                if (v < 25){
                    float* op = out + (size_t)n*768000 + (size_t)d*3000 + t*25 + v;
                    op[0]    = pc[i][nt][0] + b0;
                    op[3000] = pc[i][nt][1] + b1;
                    op[6000] = pc[i][nt][2] + b2;
                    op[9000] = pc[i][nt][3] + b3;
                }
            }
        }
    }
}

// ============== FALLBACK: fused kernel (R7, 303us) ==========================
__launch_bounds__(512, 4)
__global__ void mhsa_main(const float* __restrict__ x, const float* __restrict__ e,
                          const float* __restrict__ outer, const float* __restrict__ alpha,
                          const float* __restrict__ bproj, const u16* __restrict__ wpk,
                          float* __restrict__ out)
{
    __shared__ __align__(16) u16 smem[6656*3 + 64];
    u16* xs  = smem;
    u16* es  = smem + 6656;
    u16* opk = smem + 13312;

    const int tid = threadIdx.x;
    const int w = tid >> 6, lane = tid & 63;
    const int l15 = lane & 15, kg = lane >> 4;
    const int wg = (blockIdx.x & 7) * 480 + (blockIdx.x >> 3);
    const int n = wg / 120, t = wg % 120;
    const float alpha0 = alpha[0];
    const f32x4 zf = {0.f, 0.f, 0.f, 0.f};

    const float* xb = x + (size_t)n*768000 + t*25;
    const float* eb = e + (size_t)n*768000 + t*25;
    for (int i = tid; i < 6400; i += 512){
        int c = i / 25, v = i - c*25;
        int a16 = ((c>>3)*26 + v)*8 + (c&7);
        xs[a16] = f2bf(xb[c*3000 + v]);
        es[a16] = f2bf(eb[c*3000 + v]);
    }
    __syncthreads();

    {
        const int h = w;
        f32x4 cq[2][2], ck[2][2];
        #pragma unroll
        for (int i = 0; i < 2; ++i)
            #pragma unroll
            for (int j = 0; j < 2; ++j){ cq[i][j] = zf; ck[i][j] = zf; }
        {
            const u16* wq0 = wpk + (size_t)(h*32 + l15)*256;
            const u16* wk0 = wpk + 65536 + (size_t)(h*32 + l15)*256;
            #pragma unroll
            for (int ks = 0; ks < 8; ++ks){
                bf16x8 b0 = *(const bf16x8*)&xs[((ks*4+kg)*26 + l15)*8];
                bf16x8 b1 = *(const bf16x8*)&xs[((ks*4+kg)*26 + 16 + l15)*8];
                bf16x8 aq0 = *(const bf16x8*)(wq0 + ks*32 + kg*8);
                bf16x8 aq1 = *(const bf16x8*)(wq0 + 4096 + ks*32 + kg*8);
                bf16x8 ak0 = *(const bf16x8*)(wk0 + ks*32 + kg*8);
                bf16x8 ak1 = *(const bf16x8*)(wk0 + 4096 + ks*32 + kg*8);
                cq[0][0]=MFMA(aq0,b0,cq[0][0]); cq[0][1]=MFMA(aq0,b1,cq[0][1]);
                cq[1][0]=MFMA(aq1,b0,cq[1][0]); cq[1][1]=MFMA(aq1,b1,cq[1][1]);
                ck[0][0]=MFMA(ak0,b0,ck[0][0]); ck[0][1]=MFMA(ak0,b1,ck[0][1]);
                ck[1][0]=MFMA(ak1,b0,ck[1][0]); ck[1][1]=MFMA(ak1,b1,ck[1][1]);
            }
        }
        uint2 P_q[2][2], P_k[2][2];
        #pragma unroll
        for (int mt = 0; mt < 2; ++mt)
            #pragma unroll
            for (int nt = 0; nt < 2; ++nt){
                int coct = h*4 + mt*2 + (kg>>1);
                uint2 ev = *(const uint2*)&es[(coct*26 + nt*16 + l15)*8 + (kg&1)*4];
                ck[mt][nt][0] += bf2f(ev.x & 0xFFFFu);
                ck[mt][nt][1] += bf2f(ev.x >> 16);
                ck[mt][nt][2] += bf2f(ev.y & 0xFFFFu);
                ck[mt][nt][3] += bf2f(ev.y >> 16);
                uint2 pq; pq.x = pk2(cq[mt][nt][0], cq[mt][nt][1]);
                pq.y = pk2(cq[mt][nt][2], cq[mt][nt][3]);
                P_q[nt][mt] = pq;
                uint2 pk; pk.x = pk2(ck[mt][nt][0], ck[mt][nt][1]);
                pk.y = pk2(ck[mt][nt][2], ck[mt][nt][3]);
                P_k[nt][mt] = pk;
            }
        float bias01[2];
        {
            bf16x8 aw1 = *(const bf16x8*)(wpk + 263424 + h*32 + kg*8);
            bf16x8 be0 = *(const bf16x8*)&es[((h*4+kg)*26 + l15)*8];
            bf16x8 be1 = *(const bf16x8*)&es[((h*4+kg)*26 + 16 + l15)*8];
            f32x4 cb0 = MFMA(aw1, be0, zf);
            f32x4 cb1 = MFMA(aw1, be1, zf);
            bias01[0] = cb0[0]; bias01[1] = cb1[0];
        }
        f32x4 cv[2][2];
        #pragma unroll
        for (int i = 0; i < 2; ++i)
            #pragma unroll
            for (int j = 0; j < 2; ++j) cv[i][j] = zf;
        {
            const u16* wvt = wpk + 267776 + h*8192;
            #pragma unroll
            for (int ks = 0; ks < 8; ++ks){
                bf16x8 a0 = *(const bf16x8*)&xs[((ks*4+kg)*26 + l15)*8];
                bf16x8 a1 = *(const bf16x8*)&xs[((ks*4+kg)*26 + 16 + l15)*8];
                bf16x8 bv0 = *(const bf16x8*)&wvt[((ks*4+kg)*32 + l15)*8];
                bf16x8 bv1 = *(const bf16x8*)&wvt[((ks*4+kg)*32 + 16 + l15)*8];
                cv[0][0]=MFMA(a0,bv0,cv[0][0]); cv[0][1]=MFMA(a0,bv1,cv[0][1]);
                cv[1][0]=MFMA(a1,bv0,cv[1][0]); cv[1][1]=MFMA(a1,bv1,cv[1][1]);
            }
        }
        #pragma unroll
        for (int nt = 0; nt < 2; ++nt)
            #pragma unroll
            for (int r = 0; r < 4; ++r)
                cv[1][nt][r] = (kg*4 + r < 9) ? cv[1][nt][r] : 0.f;
        uint2 P_v[2][2];
        #pragma unroll
        for (int mt = 0; mt < 2; ++mt)
            #pragma unroll
            for (int nt = 0; nt < 2; ++nt){
                uint2 pv; pv.x = pk2(cv[mt][nt][0], cv[mt][nt][1]);
                pv.y = pk2(cv[mt][nt][2], cv[mt][nt][3]);
                P_v[nt][mt] = pv;
            }
        bf16x8 fq0  = frag8(P_q[0][0], P_q[0][1], kg, l15);
        bf16x8 fq1  = frag8(P_q[1][0], P_q[1][1], kg, l15);
        bf16x8 fke0 = frag8(P_k[0][0], P_k[0][1], kg, l15);
        bf16x8 fke1 = frag8(P_k[1][0], P_k[1][1], kg, l15);
        if (l15 >= 9){
            if (l15 <= 13)
                fke1 = *(const bf16x8*)(wpk + 262144 + ((l15-9)*8 + h)*32 + kg*8);
            else {
                union { u32 u[4]; bf16x8 v; } z; z.u[0]=z.u[1]=z.u[2]=z.u[3]=0;
                fke1 = z.v;
            }
        }
        f32x4 sc[2][2];
        sc[0][0] = MFMA(fke0, fq0, zf);
        sc[0][1] = MFMA(fke0, fq1, zf);
        sc[1][0] = MFMA(fke1, fq0, zf);
        sc[1][1] = MFMA(fke1, fq1, zf);
        uint2 P_G[2][2];
        #pragma unroll
        for (int nt = 0; nt < 2; ++nt){
            const int a = nt*16 + l15;
            f32x4 s0 = sc[0][nt], s1 = sc[1][nt];
            float rr0 = __shfl(s1[1], 32 + l15, 64);
            float rr1 = __shfl(s1[2], 32 + l15, 64);
            float rr2 = __shfl(s1[3], 32 + l15, 64);
            float rr3 = __shfl(s1[0], 48 + l15, 64);
            float rr4 = __shfl(s1[1], 48 + l15, 64);
            float tv[8];
            #pragma unroll
            for (int mt = 0; mt < 2; ++mt)
                #pragma unroll
                for (int r = 0; r < 4; ++r){
                    int b = mt*16 + kg*4 + r;
                    float sval = mt ? s1[r] : s0[r];
                    float bb = __shfl(bias01[mt], (lane & 48) + (b & 15), 64);
                    int d = a - b; d = d < 0 ? -d : d; if (d > 4) d = 4;
                    float rj = d==0?rr0 : d==1?rr1 : d==2?rr2 : d==3?rr3 : rr4;
                    float tt = (sval + rj + bb) * SCALE_;
                    tv[mt*4+r] = (b < 25) ? tt : -1e30f;
                }
            float m = tv[0];
            #pragma unroll
            for (int i = 1; i < 8; ++i) m = fmaxf(m, tv[i]);
            m = fmaxf(m, __shfl_xor(m, 16, 64));
            m = fmaxf(m, __shfl_xor(m, 32, 64));
            float ex[8], sm = 0.f;
            #pragma unroll
            for (int i = 0; i < 8; ++i){ ex[i] = __expf(tv[i] - m); sm += ex[i]; }
            sm += __shfl_xor(sm, 16, 64);
            sm += __shfl_xor(sm, 32, 64);
            const float inv = alpha0 / sm;
            float g[8];
            #pragma unroll
            for (int mt = 0; mt < 2; ++mt)
                #pragma unroll
                for (int r = 0; r < 4; ++r){
                    int b = mt*16 + kg*4 + r;
                    float ov = (a < 25 && b < 25) ? outer[((size_t)h*25 + a)*25 + b] : 0.f;
                    g[mt*4+r] = (b < 25) ? ex[mt*4+r]*inv + ov : 0.f;
                }
            uint2 pg0; pg0.x = pk2(g[0], g[1]); pg0.y = pk2(g[2], g[3]);
            uint2 pg1; pg1.x = pk2(g[4], g[5]); pg1.y = pk2(g[6], g[7]);
            P_G[nt][0] = pg0; P_G[nt][1] = pg1;
        }
        {
            bf16x8 fv0 = frag8(P_v[0][0], P_v[0][1], kg, l15);
            bf16x8 fv1 = frag8(P_v[1][0], P_v[1][1], kg, l15);
            bf16x8 fg0 = frag8(P_G[0][0], P_G[0][1], kg, l15);
            bf16x8 fg1 = frag8(P_G[1][0], P_G[1][1], kg, l15);
            f32x4 o[2][2];
            o[0][0] = MFMA(fv0, fg0, zf); o[0][1] = MFMA(fv0, fg1, zf);
            o[1][0] = MFMA(fv1, fg0, zf); o[1][1] = MFMA(fv1, fg1, zf);
            #pragma unroll
            for (int mt = 0; mt < 2; ++mt)
                #pragma unroll
                for (int nt = 0; nt < 2; ++nt){
                    int a = nt*16 + l15;
                    if (a < 25){
                        int coct = h*4 + mt*2 + (kg>>1);
                        u32* dst = (u32*)&opk[(coct*26 + a)*8 + (kg&1)*4];
                        dst[0] = pk2(o[mt][nt][0], o[mt][nt][1]);
                        dst[1] = pk2(o[mt][nt][2], o[mt][nt][3]);
                    }
                }
        }
    }
    __syncthreads();

    {
        f32x4 pc[2][2];
        #pragma unroll
        for (int i = 0; i < 2; ++i){ pc[i][0] = zf; pc[i][1] = zf; }
        #pragma unroll
        for (int ks = 0; ks < 8; ++ks){
            bf16x8 pb0 = *(const bf16x8*)&opk[((ks*4+kg)*26 + l15)*8];
            bf16x8 pb1 = *(const bf16x8*)&opk[((ks*4+kg)*26 + 16 + l15)*8];
            #pragma unroll
            for (int i = 0; i < 2; ++i){
                bf16x8 aw = *(const bf16x8*)(wpk + 196608 +
                                (size_t)(w*32 + i*16 + l15)*256 + ks*32 + kg*8);
                pc[i][0] = MFMA(aw, pb0, pc[i][0]);
                pc[i][1] = MFMA(aw, pb1, pc[i][1]);
            }
        }
        #pragma unroll
        for (int i = 0; i < 2; ++i){
            const int d = w*32 + i*16 + kg*4;
            float b0 = bproj[d], b1 = bproj[d+1], b2 = bproj[d+2], b3 = bproj[d+3];
            #pragma unroll
            for (int nt = 0; nt < 2; ++nt){
                int v = nt*16 + l15;
                if (v < 25){
                    float* op = out + (size_t)n*768000 + (size_t)d*3000 + t*25 + v;
                    op[0]    = pc[i][nt][0] + b0;
                    op[3000] = pc[i][nt][1] + b1;
                    op[6000] = pc[i][nt][2] + b2;
                    op[9000] = pc[i][nt][3] + b3;
                }
            }
        }
    }
}

extern "C" void kernel_launch(void* const* d_in, const int* in_sizes, int n_in,
                              void* d_out, int out_size, void* d_ws, size_t ws_size,
                              hipStream_t stream) {
    (void)in_sizes; (void)n_in; (void)out_size;
    const float* x     = (const float*)d_in[0];
    const float* e     = (const float*)d_in[1];
    const float* Wkv   = (const float*)d_in[2];
    const float* Wq    = (const float*)d_in[3];
    const float* Wproj = (const float*)d_in[4];
    const float* bproj = (const float*)d_in[5];
    const float* rpe   = (const float*)d_in[6];
    const float* w1    = (const float*)d_in[7];
    const float* outer = (const float*)d_in[8];
    const float* alpha = (const float*)d_in[9];
    float* out = (float*)d_out;
    u16* wpk = (u16*)d_ws;

    prep_kernel<<<1302, 256, 0, stream>>>(Wkv, Wq, Wproj, rpe, w1, wpk);

    const size_t need = (size_t)BIAS_U16_ * 2 + (size_t)3840*256*4 + 4096;  // ~165.8 MB
    if (ws_size >= need){
        u16* pages = wpk + PG_OFF_;
        float* bias_ws = (float*)(wpk + BIAS_U16_);
        qkv_gemm<<<2880, 512, 0, stream>>>(x, e, wpk, pages, bias_ws);
        attn_proj<<<3840, 512, 0, stream>>>(outer, alpha, bproj, wpk, pages, bias_ws, out);
    } else {
        mhsa_main<<<3840, 512, 0, stream>>>(x, e, outer, alpha, bproj, wpk, out);
    }
}